// Round 1
// baseline (864.437 us; speedup 1.0000x reference)
//
#include <hip/hip_runtime.h>

#define RDIM 14
#define CDIM 64
#define NFRAMES 4

// Block = 256 threads = 4 waves. Each wave owns ROWS_PER_WAVE consecutive rows;
// lane = output column (64 columns == 64 lanes).
constexpr int BLOCK = 256;
constexpr int WAVES_PER_BLOCK = BLOCK / 64;
constexpr int ROWS_PER_WAVE = 64;

__global__ __launch_bounds__(BLOCK) void frame_proj_kernel(
    const float* __restrict__ X,      // (batch, 14)
    const int* __restrict__ ids,      // (batch,)
    const float* __restrict__ W,      // (4, 64, 14)
    const float* __restrict__ B,      // (4, 64)
    float* __restrict__ out,          // (batch, 64)
    int batch)
{
    const int lane = threadIdx.x & 63;

    // Per-lane weight cache: w[e][k] = W[e][lane][k]. 56 VGPRs + 4 bias.
    // W is 14 KB total -> L1-resident; this is a one-time cost per thread.
    float w[NFRAMES][RDIM];
    float bb[NFRAMES];
#pragma unroll
    for (int e = 0; e < NFRAMES; ++e) {
#pragma unroll
        for (int k = 0; k < RDIM; ++k)
            w[e][k] = W[(e * CDIM + lane) * RDIM + k];
        bb[e] = B[e * CDIM + lane];
    }

    // Wave-uniform row base (readfirstlane forces SGPR so address math below
    // stays scalar -> x/ids loads become broadcast/scalar loads).
    const int wid  = __builtin_amdgcn_readfirstlane(threadIdx.x >> 6);
    const int gwid = blockIdx.x * WAVES_PER_BLOCK + wid;
    const int row0 = gwid * ROWS_PER_WAVE;
    int rend = row0 + ROWS_PER_WAVE;
    if (rend > batch) rend = batch;

    for (int r = row0; r < rend; ++r) {
        // Wave-uniform expert id -> scalar 4-way branch, no divergence.
        const int id = __builtin_amdgcn_readfirstlane(ids[r]);

        // x row: 56 B, 8B-aligned for every r (56 % 8 == 0). Uniform address.
        const float2* xr2 = (const float2*)(X + (size_t)r * RDIM);
        float xs[RDIM];
#pragma unroll
        for (int k = 0; k < 7; ++k) {
            float2 v = xr2[k];
            xs[2 * k]     = v.x;
            xs[2 * k + 1] = v.y;
        }

        auto dot = [&](const float (&wk)[RDIM], float bias) {
            float a = bias;
#pragma unroll
            for (int k = 0; k < RDIM; ++k)
                a = fmaf(xs[k], wk[k], a);
            return a;
        };

        float acc;
        if (id == 0)      acc = dot(w[0], bb[0]);
        else if (id == 1) acc = dot(w[1], bb[1]);
        else if (id == 2) acc = dot(w[2], bb[2]);
        else              acc = dot(w[3], bb[3]);

        // 64 lanes x 4B = 256B coalesced store, rows sequential per wave.
        out[(size_t)r * CDIM + lane] = acc;
    }
}

extern "C" void kernel_launch(void* const* d_in, const int* in_sizes, int n_in,
                              void* d_out, int out_size, void* d_ws, size_t ws_size,
                              hipStream_t stream) {
    const float* X   = (const float*)d_in[0];
    const int*   ids = (const int*)d_in[1];
    const float* W   = (const float*)d_in[2];
    const float* B   = (const float*)d_in[3];
    float* out = (float*)d_out;

    const int batch = in_sizes[1];  // frame_type_ids element count

    const int rows_per_block = ROWS_PER_WAVE * WAVES_PER_BLOCK;  // 256
    const int grid = (batch + rows_per_block - 1) / rows_per_block;

    frame_proj_kernel<<<grid, BLOCK, 0, stream>>>(X, ids, W, B, out, batch);
}